// Round 7
// baseline (845.626 us; speedup 1.0000x reference)
//
#include <hip/hip_runtime.h>
#include <math.h>

#define TPB   256
#define NPB   256      // nodes per bucket (shift 8)
#define MAXNB 512      // supports N <= 131072
#define BCAP  10240    // staging capacity per bucket (expected 8192, sigma~90 -> no overflow)
#define ITEMS 16       // edges per thread in phase-1 tile (625 blocks -> 2.4/CU)
#define CPAD  16       // pad bucket counters to one per 64B line

static inline int gridFor(size_t n) { return (int)((n + TPB - 1) / TPB); }

// ================= node linear transforms =================

__global__ void __launch_bounds__(TPB) k_lin1(
    const float* __restrict__ x,
    const float* __restrict__ Wl, const float* __restrict__ bl,
    const float* __restrict__ Wr, const float* __restrict__ br,
    float* __restrict__ xl, float* __restrict__ xr, int N)
{
  int idx = blockIdx.x * TPB + threadIdx.x;
  if (idx >= N * 18) return;
  int i = idx / 18, t = idx % 18;
  bool left = t < 9;
  int j = left ? t : t - 9;
  const float4* W4 = (const float4*)((left ? Wl : Wr) + j * 64);
  float s = (left ? bl : br)[j];
  const float4* xi4 = (const float4*)(x + (size_t)i * 64);
#pragma unroll
  for (int f = 0; f < 16; f++) {
    float4 xv = xi4[f], wv = W4[f];
    s = fmaf(xv.x, wv.x, s);
    s = fmaf(xv.y, wv.y, s);
    s = fmaf(xv.z, wv.z, s);
    s = fmaf(xv.w, wv.w, s);
  }
  (left ? xl : xr)[(size_t)i * 9 + j] = s;
}

__global__ void __launch_bounds__(TPB) k_lin2(
    const float* __restrict__ h1, const float* __restrict__ bias1,
    const float* __restrict__ Wl, const float* __restrict__ bl,
    const float* __restrict__ Wr, const float* __restrict__ br,
    float* __restrict__ xl, float* __restrict__ xr, int N)
{
  int idx = blockIdx.x * TPB + threadIdx.x;
  if (idx >= N * 40) return;
  int i = idx / 40, t = idx % 40;
  float hr[9];
#pragma unroll
  for (int k = 0; k < 9; k++) hr[k] = fmaxf(h1[(size_t)i * 9 + k] + bias1[k], 0.0f);
  bool left = t < 20;
  int j = left ? t : t - 20;
  const float* W = (left ? Wl : Wr) + j * 9;
  float s = (left ? bl : br)[j];
#pragma unroll
  for (int k = 0; k < 9; k++) s = fmaf(hr[k], W[k], s);
  (left ? xl : xr)[(size_t)i * 20 + j] = s;
}

// ============== phase 1: bin edges by dst-bucket (LDS multisplit) ==========
// record: x = eid | (dst_local << 22), y = src.  (E < 2^22, dst_local < 256)

__global__ void __launch_bounds__(TPB) k_bin(
    const int* __restrict__ ei, int* __restrict__ bucketCntP,
    int2* __restrict__ staging, int E, int NB)
{
  __shared__ int hist[MAXNB];
  __shared__ int base[MAXNB];
  int tid = threadIdx.x;
  size_t tile0 = (size_t)blockIdx.x * (TPB * ITEMS);
  for (int i = tid; i < NB; i += TPB) hist[i] = 0;
  __syncthreads();
  for (int it = 0; it < ITEMS; ++it) {
    size_t e = tile0 + (size_t)it * TPB + tid;
    if (e < (size_t)E) {
      int dst = ei[(size_t)E + e];
      atomicAdd(&hist[dst >> 8], 1);
    }
  }
  __syncthreads();
  for (int i = tid; i < NB; i += TPB) {
    int c = hist[i];
    base[i] = c ? atomicAdd(&bucketCntP[(size_t)i * CPAD], c) : 0;
    hist[i] = 0;
  }
  __syncthreads();
  for (int it = 0; it < ITEMS; ++it) {
    size_t e = tile0 + (size_t)it * TPB + tid;
    if (e < (size_t)E) {
      int src = ei[e];
      int dst = ei[(size_t)E + e];
      int b = dst >> 8;
      int r = atomicAdd(&hist[b], 1);
      staging[(size_t)b * BCAP + base[b] + r] =
          make_int2((int)e | ((dst & 255) << 22), src);
    }
  }
}

// ============== scan bucket counts -> bucket edge bases ==============

__global__ void __launch_bounds__(MAXNB) k_scanb(
    const int* __restrict__ bucketCntP, int* __restrict__ bucketBase, int NB)
{
  __shared__ int s[MAXNB];
  int tid = threadIdx.x;
  int v = (tid < NB) ? bucketCntP[(size_t)tid * CPAD] : 0;
  s[tid] = v;
  __syncthreads();
  for (int off = 1; off < MAXNB; off <<= 1) {
    int u = (tid >= off) ? s[tid - off] : 0;
    __syncthreads();
    s[tid] += u;
    __syncthreads();
  }
  if (tid < NB) bucketBase[tid] = s[tid] - v;   // exclusive
}

// ============== phase 2: per-bucket tight CSR (L2-local writes) ============

__global__ void __launch_bounds__(TPB) k_csr(
    const int2* __restrict__ staging, const int* __restrict__ bucketCntP,
    const int* __restrict__ bucketBase,
    int* __restrict__ rowptr, int* __restrict__ degO,
    int* __restrict__ src_csr, int* __restrict__ eid_csr, int N)
{
  int b = blockIdx.x, tid = threadIdx.x;
  int n0 = b << 8;
  int recCnt = bucketCntP[(size_t)b * CPAD];
  int ebase = bucketBase[b];
  const int2* rec = staging + (size_t)b * BCAP;
  __shared__ int deg_s[NPB];
  __shared__ int pfx[NPB];
  __shared__ int cur[NPB];
  deg_s[tid] = 0;
  __syncthreads();
  for (int r = tid; r < recCnt; r += TPB)
    atomicAdd(&deg_s[(rec[r].x >> 22) & 255], 1);
  __syncthreads();
  pfx[tid] = deg_s[tid];
  __syncthreads();
  for (int off = 1; off < NPB; off <<= 1) {
    int u = (tid >= off) ? pfx[tid - off] : 0;
    __syncthreads();
    pfx[tid] += u;
    __syncthreads();
  }
  int excl = pfx[tid] - deg_s[tid];
  int n = n0 + tid;
  if (n < N) { rowptr[n] = ebase + excl; degO[n] = deg_s[tid]; }
  cur[tid] = ebase + excl;
  __syncthreads();
  for (int r = tid; r < recCnt; r += TPB) {
    int2 rc = rec[r];
    int dl = (rc.x >> 22) & 255;
    int eid = rc.x & 0x3FFFFF;
    int pos = atomicAdd(&cur[dl], 1);
    src_csr[pos] = rc.y;
    eid_csr[pos] = eid;
  }
}

// ============== gather-reorder eattr into CSR order ==============
// lane-cooperative: 4 lanes per edge, each moves one float4 -> the 4 lanes'
// 16B reads of the same 64B line coalesce into one transaction, and the
// stores are dense float4 streams.  (Proven shape: fast in rounds 2/6.)

__global__ void __launch_bounds__(TPB) k_reorder(
    const int* __restrict__ eid_csr, const float4* __restrict__ eattr4,
    float4* __restrict__ eac, int E)
{
  int idx = blockIdx.x * TPB + threadIdx.x;
  int slot = idx >> 2;
  int part = idx & 3;
  if (slot >= E) return;
  int eid = eid_csr[slot];                  // broadcast across the 4 lanes
  eac[(size_t)slot * 4 + part] = eattr4[(size_t)eid * 4 + part];
}

// ========== fused GATv2 attention (SEQ path): f-split-4 cooperative =======
// 4 lanes per (node, head) row.  Lane l holds only w[C][4] (f in [4l,4l+4))
// instead of the full C x 16 matrix (fixes the VGPR-129-live / remat problem
// seen at VGPR_Count=76).  The group processes 4 consecutive edges jointly:
// lane l loads quarter l of each of the 4 attr rows (one coalesced 64B
// transaction per row), computes partial dots, and a 2-step quad-local
// shfl_xor butterfly (DPP, no LDS) yields every edge's full projection in
// every lane (addition commutativity -> bitwise-identical across lanes).
// Lane l then runs the online-softmax update for edge p0+l, exactly the
// same per-lane edge assignment as before; end-of-loop merge unchanged.

template <int H, int C>
__global__ void __launch_bounds__(TPB) k_attn4(
    const int* __restrict__ rowptr, const int* __restrict__ deg,
    const int* __restrict__ src_csr,
    const float* __restrict__ eac,      // CSR-slot-ordered edge attrs
    const float* __restrict__ xl, const float* __restrict__ xr,
    const float* __restrict__ We, const float* __restrict__ att,
    const float* __restrict__ bias,     // nullptr -> raw output
    float* __restrict__ out, int N)
{
  constexpr int HC = H * C;
  int idx = blockIdx.x * TPB + threadIdx.x;
  if (idx >= N * H * 4) return;
  int l = idx & 3;                 // lane within quad group
  int g = idx >> 2;                // (node, head) group
  int n = g / H, h = g - n * H;

  // quarter weight rows: w[c][k] = We[(h*C+c)*16 + 4*l + k]
  float w[C][4];
#pragma unroll
  for (int c = 0; c < C; c++) {
    const float* wr = We + (h * C + c) * 16 + 4 * l;
#pragma unroll
    for (int k = 0; k < 4; k++) w[c][k] = wr[k];
  }
  float attv[C], xrv[C];
#pragma unroll
  for (int c = 0; c < C; c++) {
    attv[c] = att[h * C + c];
    xrv[c] = xr[(size_t)n * HC + h * C + c];
  }

  int r0 = rowptr[n];
  int dg = deg[n];

  float mx = -3.0e38f, den = 0.0f;
  float acc[C], ea_sum[C];
#pragma unroll
  for (int c = 0; c < C; c++) { acc[c] = 0.0f; ea_sum[c] = 0.0f; }

  for (int p0 = 0; p0 < dg; p0 += 4) {
    // quarter-l of the 4 consecutive attr rows (guard tail with zeros)
    float4 zq = make_float4(0.f, 0.f, 0.f, 0.f);
    float4 a0 = (p0 + 0 < dg) ? *(const float4*)(eac + ((size_t)(r0 + p0 + 0) * 16 + 4 * l)) : zq;
    float4 a1 = (p0 + 1 < dg) ? *(const float4*)(eac + ((size_t)(r0 + p0 + 1) * 16 + 4 * l)) : zq;
    float4 a2 = (p0 + 2 < dg) ? *(const float4*)(eac + ((size_t)(r0 + p0 + 2) * 16 + 4 * l)) : zq;
    float4 a3 = (p0 + 3 < dg) ? *(const float4*)(eac + ((size_t)(r0 + p0 + 3) * 16 + 4 * l)) : zq;

    // own edge metadata (lane l owns edge p0+l)
    int myp = p0 + l;
    bool mine = myp < dg;
    int pos = r0 + (mine ? myp : 0);          // r0 valid since p0 < dg
    int srcn = src_csr[pos];
    const float* xs = xl + (size_t)srcn * HC + h * C;
    float xv[C];
#pragma unroll
    for (int c = 0; c < C; c++) xv[c] = xs[c];

    float lg = 0.0f;
#pragma unroll
    for (int c = 0; c < C; c++) {
      // partial dots (each lane: its f-quarter of all 4 edges)
      float d0 = fmaf(a0.w, w[c][3], fmaf(a0.z, w[c][2], fmaf(a0.y, w[c][1], a0.x * w[c][0])));
      float d1 = fmaf(a1.w, w[c][3], fmaf(a1.z, w[c][2], fmaf(a1.y, w[c][1], a1.x * w[c][0])));
      float d2 = fmaf(a2.w, w[c][3], fmaf(a2.z, w[c][2], fmaf(a2.y, w[c][1], a2.x * w[c][0])));
      float d3 = fmaf(a3.w, w[c][3], fmaf(a3.z, w[c][2], fmaf(a3.y, w[c][1], a3.x * w[c][0])));
      // quad butterfly: full dot of each edge in every lane
      d0 += __shfl_xor(d0, 1, 4);  d1 += __shfl_xor(d1, 1, 4);
      d2 += __shfl_xor(d2, 1, 4);  d3 += __shfl_xor(d3, 1, 4);
      d0 += __shfl_xor(d0, 2, 4);  d1 += __shfl_xor(d1, 2, 4);
      d2 += __shfl_xor(d2, 2, 4);  d3 += __shfl_xor(d3, 2, 4);
      // own edge's projection channel
      float eav = (l & 2) ? ((l & 1) ? d3 : d2) : ((l & 1) ? d1 : d0);
      ea_sum[c] += mine ? eav : 0.0f;
      float m = xv[c] + xrv[c] + eav;
      m = (m >= 0.0f) ? m : 0.2f * m;
      lg = fmaf(m, attv[c], lg);
    }
    if (mine) {
      float nm = fmaxf(mx, lg);
      float s = expf(mx - nm);
      float wE = expf(lg - nm);
      den = den * s + wE;
#pragma unroll
      for (int c = 0; c < C; c++) acc[c] = fmaf(acc[c], s, wE * xv[c]);
      mx = nm;
    }
  }

  // ---- merge the 4 partial online-softmax states (quad butterfly) ----
#pragma unroll
  for (int off = 1; off < 4; off <<= 1) {
    float omx  = __shfl_xor(mx, off, 4);
    float oden = __shfl_xor(den, off, 4);
    float nm = fmaxf(mx, omx);
    float s1 = expf(mx - nm);    // both sentinel -> exp(0)=1, scales zeros
    float s2 = expf(omx - nm);
    den = den * s1 + oden * s2;
#pragma unroll
    for (int c = 0; c < C; c++) {
      float oa = __shfl_xor(acc[c], off, 4);
      float oe = __shfl_xor(ea_sum[c], off, 4);
      acc[c] = acc[c] * s1 + oa * s2;
      ea_sum[c] += oe;
    }
    mx = nm;
  }

  // virtual self-loop: src = n, attr projection = mean of edge projections
  {
    float invd = 1.0f / fmaxf((float)dg, 1.0f);
    const float* xs = xl + (size_t)n * HC + h * C;
    float xv[C];
#pragma unroll
    for (int c = 0; c < C; c++) xv[c] = xs[c];
    float lg = 0.0f;
#pragma unroll
    for (int c = 0; c < C; c++) {
      float m = xv[c] + xrv[c] + ea_sum[c] * invd;
      m = (m >= 0.0f) ? m : 0.2f * m;
      lg = fmaf(m, attv[c], lg);
    }
    float nm = fmaxf(mx, lg);
    float s = expf(mx - nm);
    float wE = expf(lg - nm);
    den = den * s + wE;
#pragma unroll
    for (int c = 0; c < C; c++) acc[c] = fmaf(acc[c], s, wE * xv[c]);
  }

  float inv = 1.0f / den;
  float* od = out + (size_t)n * HC + h * C;
  for (int c = l; c < C; c += 4) {
    float v = acc[c] * inv;
    if (bias) v = fmaxf(v + bias[h * C + c], 0.0f);
    od[c] = v;
  }
}

// ========== fallback attention (ws too small): raw-attr gather, L=4 =======

template <int H, int C>
__global__ void __launch_bounds__(TPB) k_attn_raw(
    const int* __restrict__ rowptr, const int* __restrict__ deg,
    const int* __restrict__ src_csr, const int* __restrict__ eid_csr,
    const float* __restrict__ eattr,
    const float* __restrict__ xl, const float* __restrict__ xr,
    const float* __restrict__ We, const float* __restrict__ att,
    const float* __restrict__ bias,
    float* __restrict__ out, int N)
{
  constexpr int HC = H * C;
  constexpr int L = 4;
  int idx = blockIdx.x * TPB + threadIdx.x;
  if (idx >= N * H * L) return;
  int l = idx & (L - 1);
  int g = idx / L;
  int n = g / H, h = g - n * H;

  float w[C][16];
#pragma unroll
  for (int c = 0; c < C; c++)
#pragma unroll
    for (int f = 0; f < 16; f++) w[c][f] = We[(h * C + c) * 16 + f];
  float attv[C], xrv[C];
#pragma unroll
  for (int c = 0; c < C; c++) {
    attv[c] = att[h * C + c];
    xrv[c] = xr[(size_t)n * HC + h * C + c];
  }

  int r0 = rowptr[n];
  int dg = deg[n];
  float mx = -3.0e38f, den = 0.0f;
  float acc[C], ea_sum[C];
#pragma unroll
  for (int c = 0; c < C; c++) { acc[c] = 0.0f; ea_sum[c] = 0.0f; }

  for (int p = l; p < dg; p += L) {
    int pos = r0 + p;
    float a[16];
    const float4* a4 = (const float4*)(eattr + (size_t)eid_csr[pos] * 16);
#pragma unroll
    for (int k = 0; k < 4; k++) {
      float4 v = a4[k];
      a[4 * k + 0] = v.x; a[4 * k + 1] = v.y; a[4 * k + 2] = v.z; a[4 * k + 3] = v.w;
    }
    int srcn = src_csr[pos];
    const float* xs = xl + (size_t)srcn * HC + h * C;
    float xv[C];
#pragma unroll
    for (int c = 0; c < C; c++) xv[c] = xs[c];
    float lg = 0.0f;
#pragma unroll
    for (int c = 0; c < C; c++) {
      float ea = 0.0f;
#pragma unroll
      for (int f = 0; f < 16; f++) ea = fmaf(a[f], w[c][f], ea);
      ea_sum[c] += ea;
      float m = xv[c] + xrv[c] + ea;
      m = (m >= 0.0f) ? m : 0.2f * m;
      lg = fmaf(m, attv[c], lg);
    }
    float nm = fmaxf(mx, lg);
    float s = expf(mx - nm);
    float wE = expf(lg - nm);
    den = den * s + wE;
#pragma unroll
    for (int c = 0; c < C; c++) acc[c] = fmaf(acc[c], s, wE * xv[c]);
    mx = nm;
  }

#pragma unroll
  for (int off = 1; off < L; off <<= 1) {
    float omx  = __shfl_xor(mx, off, 4);
    float oden = __shfl_xor(den, off, 4);
    float nm = fmaxf(mx, omx);
    float s1 = expf(mx - nm);
    float s2 = expf(omx - nm);
    den = den * s1 + oden * s2;
#pragma unroll
    for (int c = 0; c < C; c++) {
      float oa = __shfl_xor(acc[c], off, 4);
      float oe = __shfl_xor(ea_sum[c], off, 4);
      acc[c] = acc[c] * s1 + oa * s2;
      ea_sum[c] += oe;
    }
    mx = nm;
  }

  {
    float invd = 1.0f / fmaxf((float)dg, 1.0f);
    const float* xs = xl + (size_t)n * HC + h * C;
    float xv[C];
#pragma unroll
    for (int c = 0; c < C; c++) xv[c] = xs[c];
    float lg = 0.0f;
#pragma unroll
    for (int c = 0; c < C; c++) {
      float m = xv[c] + xrv[c] + ea_sum[c] * invd;
      m = (m >= 0.0f) ? m : 0.2f * m;
      lg = fmaf(m, attv[c], lg);
    }
    float nm = fmaxf(mx, lg);
    float s = expf(mx - nm);
    float wE = expf(lg - nm);
    den = den * s + wE;
#pragma unroll
    for (int c = 0; c < C; c++) acc[c] = fmaf(acc[c], s, wE * xv[c]);
  }

  float inv = 1.0f / den;
  float* od = out + (size_t)n * HC + h * C;
  for (int c = l; c < C; c += L) {
    float v = acc[c] * inv;
    if (bias) v = fmaxf(v + bias[h * C + c], 0.0f);
    od[c] = v;
  }
}

// ================= FC head =================

__global__ void __launch_bounds__(TPB) k_fc1(
    const float* __restrict__ h2, const float* __restrict__ W,
    float* __restrict__ h3, int NN, int Kc)
{
  int o = blockIdx.x;
  int ks = blockIdx.y;
  int k0 = ks * Kc;
  int k1 = min(NN, k0 + Kc);
  float acc[16];
#pragma unroll
  for (int b = 0; b < 16; b++) acc[b] = 0.0f;
  const float* wo = W + (size_t)o * NN;
  for (int k = k0 + threadIdx.x; k < k1; k += TPB) {
    float w = wo[k];
#pragma unroll
    for (int b = 0; b < 16; b++) acc[b] = fmaf(h2[(size_t)b * NN + k], w, acc[b]);
  }
#pragma unroll
  for (int b = 0; b < 16; b++) {
    float v = acc[b];
#pragma unroll
    for (int off = 32; off > 0; off >>= 1) v += __shfl_down(v, off, 64);
    if ((threadIdx.x & 63) == 0) atomicAdd(&h3[b * 100 + o], v);
  }
}

__global__ void __launch_bounds__(TPB) k_fc23(
    const float* __restrict__ h3, const float* __restrict__ fcb1,
    const float* __restrict__ W2, const float* __restrict__ b2,
    const float* __restrict__ W3, const float* __restrict__ b3,
    float* __restrict__ out, int B)
{
  __shared__ float s3[32 * 100];
  __shared__ float s4[32 * 10];
  int tid = threadIdx.x;
  for (int t = tid; t < B * 100; t += TPB)
    s3[t] = fmaxf(h3[t] + fcb1[t % 100], 0.0f);
  __syncthreads();
  if (tid < B * 10) {
    int b = tid / 10, o = tid % 10;
    float s = b2[o];
#pragma unroll
    for (int k = 0; k < 100; k++) s = fmaf(s3[b * 100 + k], W2[o * 100 + k], s);
    s4[tid] = fmaxf(s, 0.0f);
  }
  __syncthreads();
  if (tid < B) {
    float s = b3[0];
#pragma unroll
    for (int k = 0; k < 10; k++) s = fmaf(s4[tid * 10 + k], W3[k], s);
    out[tid] = s;
  }
}

// ================= launch =================

extern "C" void kernel_launch(void* const* d_in, const int* in_sizes, int n_in,
                              void* d_out, int out_size, void* d_ws, size_t ws_size,
                              hipStream_t stream) {
  const float* x      = (const float*)d_in[0];
  const int*   ei     = (const int*)d_in[1];
  const float* eattr  = (const float*)d_in[2];
  const float* W1l = (const float*)d_in[4];  const float* b1l = (const float*)d_in[5];
  const float* W1r = (const float*)d_in[6];  const float* b1r = (const float*)d_in[7];
  const float* We1 = (const float*)d_in[8];  const float* att1 = (const float*)d_in[9];
  const float* bias1 = (const float*)d_in[10];
  const float* W2l = (const float*)d_in[11]; const float* b2l = (const float*)d_in[12];
  const float* W2r = (const float*)d_in[13]; const float* b2r = (const float*)d_in[14];
  const float* We2 = (const float*)d_in[15]; const float* att2 = (const float*)d_in[16];
  const float* bias2 = (const float*)d_in[17];
  const float* fcW1 = (const float*)d_in[18]; const float* fcb1 = (const float*)d_in[19];
  const float* fcW2 = (const float*)d_in[20]; const float* fcb2 = (const float*)d_in[21];
  const float* fcW3 = (const float*)d_in[22]; const float* fcb3 = (const float*)d_in[23];
  float* out = (float*)d_out;

  const int N = in_sizes[0] / 64;                   // 80000
  const int E = in_sizes[2] / 16;                   // 2560000
  const int num_nodes = in_sizes[18] / (100 * 20);  // 5000
  const int B = N / num_nodes;                      // 16
  const int NB = (N + NPB - 1) / NPB;               // 313

  // ---- workspace layout (64B aligned chunks) ----
  char* base = (char*)d_ws;
  size_t off = 0;
  auto alloc = [&](size_t bytes) {
    size_t o = off; off += (bytes + 63) & ~(size_t)63; return o;
  };
  // zero-init region: padded bucket counters + h3
  size_t o_bcnt   = alloc((size_t)NB * CPAD * 4);
  size_t o_h3     = alloc((size_t)B * 100 * 4);
  size_t zeroBytes = off;
  size_t o_bbase  = alloc((size_t)NB * 4);
  size_t o_stage  = alloc((size_t)NB * BCAP * 8);
  size_t o_rowptr = alloc((size_t)N * 4);
  size_t o_deg    = alloc((size_t)N * 4);
  size_t o_srcc   = alloc((size_t)E * 4);
  size_t o_eidc   = alloc((size_t)E * 4);
  size_t o_xl1    = alloc((size_t)N * 9 * 4);
  size_t o_xr1    = alloc((size_t)N * 9 * 4);
  size_t o_xl2    = alloc((size_t)N * 20 * 4);
  size_t o_xr2    = alloc((size_t)N * 20 * 4);
  size_t o_h1     = alloc((size_t)N * 9 * 4);
  size_t o_h2     = alloc((size_t)N * 20 * 4);
  size_t o_eac    = alloc((size_t)E * 16 * 4);      // 164 MB, optional
  bool seq = (off <= ws_size);                      // reorder only if ws fits

  int*   bcnt   = (int*)(base + o_bcnt);
  float* h3     = (float*)(base + o_h3);
  int*   bbase  = (int*)(base + o_bbase);
  int2*  stage  = (int2*)(base + o_stage);
  int*   rowptr = (int*)(base + o_rowptr);
  int*   deg    = (int*)(base + o_deg);
  int*   srcc   = (int*)(base + o_srcc);
  int*   eidc   = (int*)(base + o_eidc);
  float* xl1    = (float*)(base + o_xl1);
  float* xr1    = (float*)(base + o_xr1);
  float* xl2    = (float*)(base + o_xl2);
  float* xr2    = (float*)(base + o_xr2);
  float* h1     = (float*)(base + o_h1);
  float* h2     = (float*)(base + o_h2);
  float* eac    = (float*)(base + o_eac);

  hipMemsetAsync(d_ws, 0, zeroBytes, stream);

  // node linears layer 1 (independent)
  k_lin1<<<gridFor((size_t)N * 18), TPB, 0, stream>>>(x, W1l, b1l, W1r, b1r, xl1, xr1, N);

  // binned CSR build
  int binBlocks = (int)(((size_t)E + TPB * ITEMS - 1) / (TPB * ITEMS));
  k_bin<<<binBlocks, TPB, 0, stream>>>(ei, bcnt, stage, E, NB);
  k_scanb<<<1, MAXNB, 0, stream>>>(bcnt, bbase, NB);
  k_csr<<<NB, TPB, 0, stream>>>(stage, bcnt, bbase, rowptr, deg, srcc, eidc, N);
  if (seq)
    k_reorder<<<gridFor((size_t)E * 4), TPB, 0, stream>>>(
        eidc, (const float4*)eattr, (float4*)eac, E);

  // ---- GATv2 layer 1 (H=3, C=3), f-split-4 cooperative ----
  if (seq)
    k_attn4<3, 3><<<gridFor((size_t)N * 3 * 4), TPB, 0, stream>>>(
        rowptr, deg, srcc, eac, xl1, xr1, We1, att1, nullptr, h1, N);
  else
    k_attn_raw<3, 3><<<gridFor((size_t)N * 3 * 4), TPB, 0, stream>>>(
        rowptr, deg, srcc, eidc, eattr, xl1, xr1, We1, att1, nullptr, h1, N);

  // node linears layer 2
  k_lin2<<<gridFor((size_t)N * 40), TPB, 0, stream>>>(h1, bias1, W2l, b2l, W2r, b2r, xl2, xr2, N);

  // ---- GATv2 layer 2 (H=4, C=5), fused bias2+relu ----
  if (seq)
    k_attn4<4, 5><<<gridFor((size_t)N * 4 * 4), TPB, 0, stream>>>(
        rowptr, deg, srcc, eac, xl2, xr2, We2, att2, bias2, h2, N);
  else
    k_attn_raw<4, 5><<<gridFor((size_t)N * 4 * 4), TPB, 0, stream>>>(
        rowptr, deg, srcc, eidc, eattr, xl2, xr2, We2, att2, bias2, h2, N);

  // FC head
  const int NN = num_nodes * 20;   // 100000
  const int KS = 16;
  const int Kc = (NN + KS - 1) / KS;
  dim3 g1(100, KS);
  k_fc1<<<g1, TPB, 0, stream>>>(h2, fcW1, h3, NN, Kc);
  k_fc23<<<1, TPB, 0, stream>>>(h3, fcb1, fcW2, fcb2, fcW3, fcb3, out, B);
  (void)out_size; (void)n_in;
}

// Round 8
// 749.505 us; speedup vs baseline: 1.1282x; 1.1282x over previous
//
#include <hip/hip_runtime.h>
#include <math.h>

#define TPB   256
#define NPB   256      // nodes per bucket (shift 8)
#define MAXNB 512      // supports N <= 131072
#define BCAP  10240    // staging capacity per bucket (expected 8192, sigma~90 -> no overflow)
#define ITEMS 16       // edges per thread in phase-1 tile (625 blocks -> 2.4/CU)
#define CPAD  16       // pad bucket counters to one per 64B line

static inline int gridFor(size_t n) { return (int)((n + TPB - 1) / TPB); }

// ================= node linear transforms =================

__global__ void __launch_bounds__(TPB) k_lin1(
    const float* __restrict__ x,
    const float* __restrict__ Wl, const float* __restrict__ bl,
    const float* __restrict__ Wr, const float* __restrict__ br,
    float* __restrict__ xl, float* __restrict__ xr, int N)
{
  int idx = blockIdx.x * TPB + threadIdx.x;
  if (idx >= N * 18) return;
  int i = idx / 18, t = idx % 18;
  bool left = t < 9;
  int j = left ? t : t - 9;
  const float4* W4 = (const float4*)((left ? Wl : Wr) + j * 64);
  float s = (left ? bl : br)[j];
  const float4* xi4 = (const float4*)(x + (size_t)i * 64);
#pragma unroll
  for (int f = 0; f < 16; f++) {
    float4 xv = xi4[f], wv = W4[f];
    s = fmaf(xv.x, wv.x, s);
    s = fmaf(xv.y, wv.y, s);
    s = fmaf(xv.z, wv.z, s);
    s = fmaf(xv.w, wv.w, s);
  }
  (left ? xl : xr)[(size_t)i * 9 + j] = s;
}

__global__ void __launch_bounds__(TPB) k_lin2(
    const float* __restrict__ h1, const float* __restrict__ bias1,
    const float* __restrict__ Wl, const float* __restrict__ bl,
    const float* __restrict__ Wr, const float* __restrict__ br,
    float* __restrict__ xl, float* __restrict__ xr, int N)
{
  int idx = blockIdx.x * TPB + threadIdx.x;
  if (idx >= N * 40) return;
  int i = idx / 40, t = idx % 40;
  float hr[9];
#pragma unroll
  for (int k = 0; k < 9; k++) hr[k] = fmaxf(h1[(size_t)i * 9 + k] + bias1[k], 0.0f);
  bool left = t < 20;
  int j = left ? t : t - 20;
  const float* W = (left ? Wl : Wr) + j * 9;
  float s = (left ? bl : br)[j];
#pragma unroll
  for (int k = 0; k < 9; k++) s = fmaf(hr[k], W[k], s);
  (left ? xl : xr)[(size_t)i * 20 + j] = s;
}

// ============== phase 1: bin edges by dst-bucket (LDS multisplit) ==========
// record: x = eid | (dst_local << 22), y = src.  (E < 2^22, dst_local < 256)

__global__ void __launch_bounds__(TPB) k_bin(
    const int* __restrict__ ei, int* __restrict__ bucketCntP,
    int2* __restrict__ staging, int E, int NB)
{
  __shared__ int hist[MAXNB];
  __shared__ int base[MAXNB];
  int tid = threadIdx.x;
  size_t tile0 = (size_t)blockIdx.x * (TPB * ITEMS);
  for (int i = tid; i < NB; i += TPB) hist[i] = 0;
  __syncthreads();
  for (int it = 0; it < ITEMS; ++it) {
    size_t e = tile0 + (size_t)it * TPB + tid;
    if (e < (size_t)E) {
      int dst = ei[(size_t)E + e];
      atomicAdd(&hist[dst >> 8], 1);
    }
  }
  __syncthreads();
  for (int i = tid; i < NB; i += TPB) {
    int c = hist[i];
    base[i] = c ? atomicAdd(&bucketCntP[(size_t)i * CPAD], c) : 0;
    hist[i] = 0;
  }
  __syncthreads();
  for (int it = 0; it < ITEMS; ++it) {
    size_t e = tile0 + (size_t)it * TPB + tid;
    if (e < (size_t)E) {
      int src = ei[e];
      int dst = ei[(size_t)E + e];
      int b = dst >> 8;
      int r = atomicAdd(&hist[b], 1);
      staging[(size_t)b * BCAP + base[b] + r] =
          make_int2((int)e | ((dst & 255) << 22), src);
    }
  }
}

// ============== scan bucket counts -> bucket edge bases ==============

__global__ void __launch_bounds__(MAXNB) k_scanb(
    const int* __restrict__ bucketCntP, int* __restrict__ bucketBase, int NB)
{
  __shared__ int s[MAXNB];
  int tid = threadIdx.x;
  int v = (tid < NB) ? bucketCntP[(size_t)tid * CPAD] : 0;
  s[tid] = v;
  __syncthreads();
  for (int off = 1; off < MAXNB; off <<= 1) {
    int u = (tid >= off) ? s[tid - off] : 0;
    __syncthreads();
    s[tid] += u;
    __syncthreads();
  }
  if (tid < NB) bucketBase[tid] = s[tid] - v;   // exclusive
}

// ============== phase 2: per-bucket tight CSR (L2-local writes) ============

__global__ void __launch_bounds__(TPB) k_csr(
    const int2* __restrict__ staging, const int* __restrict__ bucketCntP,
    const int* __restrict__ bucketBase,
    int* __restrict__ rowptr, int* __restrict__ degO,
    int* __restrict__ src_csr, int* __restrict__ eid_csr, int N)
{
  int b = blockIdx.x, tid = threadIdx.x;
  int n0 = b << 8;
  int recCnt = bucketCntP[(size_t)b * CPAD];
  int ebase = bucketBase[b];
  const int2* rec = staging + (size_t)b * BCAP;
  __shared__ int deg_s[NPB];
  __shared__ int pfx[NPB];
  __shared__ int cur[NPB];
  deg_s[tid] = 0;
  __syncthreads();
  for (int r = tid; r < recCnt; r += TPB)
    atomicAdd(&deg_s[(rec[r].x >> 22) & 255], 1);
  __syncthreads();
  pfx[tid] = deg_s[tid];
  __syncthreads();
  for (int off = 1; off < NPB; off <<= 1) {
    int u = (tid >= off) ? pfx[tid - off] : 0;
    __syncthreads();
    pfx[tid] += u;
    __syncthreads();
  }
  int excl = pfx[tid] - deg_s[tid];
  int n = n0 + tid;
  if (n < N) { rowptr[n] = ebase + excl; degO[n] = deg_s[tid]; }
  cur[tid] = ebase + excl;
  __syncthreads();
  for (int r = tid; r < recCnt; r += TPB) {
    int2 rc = rec[r];
    int dl = (rc.x >> 22) & 255;
    int eid = rc.x & 0x3FFFFF;
    int pos = atomicAdd(&cur[dl], 1);
    src_csr[pos] = rc.y;
    eid_csr[pos] = eid;
  }
}

// ========== fused GATv2 attention: online softmax, virtual self-loop =======
// L lanes cooperate on one (node, head) row; each lane keeps a partial
// online-softmax state over edges p = lane, lane+L, ...; states merged via
// a shfl_xor butterfly at the end (amortized -- NO per-edge cross-lane ops;
// round-7 showed per-edge __shfl compiles to ds_bpermute on the LDS pipe
// and costs more than the FMAs it saves).
// Raw-gather path: edge attrs fetched via eid_csr from the original eattr.
// eattr (164 MB) fits in the 256 MB L3, and the H same-node head-lanes read
// identical addresses (hardware dedupe), so the gather is L3-warm.

template <int H, int C, int L>
__global__ void __launch_bounds__(TPB) k_attn(
    const int* __restrict__ rowptr, const int* __restrict__ deg,
    const int* __restrict__ src_csr, const int* __restrict__ eid_csr,
    const float* __restrict__ eattr,
    const float* __restrict__ xl, const float* __restrict__ xr,
    const float* __restrict__ We, const float* __restrict__ att,
    const float* __restrict__ bias,  // nullptr -> raw output
    float* __restrict__ out, int N)
{
  constexpr int HC = H * C;
  int idx = blockIdx.x * TPB + threadIdx.x;
  if (idx >= N * H * L) return;
  int l = idx & (L - 1);          // lane within group (L divides 64)
  int g = idx / L;                // (node, head) group
  int n = g / H, h = g - n * H;

  float w[C][16];
#pragma unroll
  for (int c = 0; c < C; c++)
#pragma unroll
    for (int f = 0; f < 16; f++) w[c][f] = We[(h * C + c) * 16 + f];
  float attv[C], xrv[C];
#pragma unroll
  for (int c = 0; c < C; c++) {
    attv[c] = att[h * C + c];
    xrv[c] = xr[(size_t)n * HC + h * C + c];
  }

  int r0 = rowptr[n];
  int dg = deg[n];

  // finite sentinel (not -inf) so empty-lane merges give exp(0)=1 on a zero
  // accumulator instead of exp(-inf+inf)=NaN.
  float mx = -3.0e38f, den = 0.0f;
  float acc[C], ea_sum[C];
#pragma unroll
  for (int c = 0; c < C; c++) { acc[c] = 0.0f; ea_sum[c] = 0.0f; }

  for (int p = l; p < dg; p += L) {
    int pos = r0 + p;
    float a[16];
    const float4* a4 = (const float4*)(eattr + (size_t)eid_csr[pos] * 16);
#pragma unroll
    for (int k = 0; k < 4; k++) {
      float4 v = a4[k];
      a[4 * k + 0] = v.x; a[4 * k + 1] = v.y; a[4 * k + 2] = v.z; a[4 * k + 3] = v.w;
    }
    int srcn = src_csr[pos];
    const float* xs = xl + (size_t)srcn * HC + h * C;
    float xv[C];
#pragma unroll
    for (int c = 0; c < C; c++) xv[c] = xs[c];
    float lg = 0.0f;
#pragma unroll
    for (int c = 0; c < C; c++) {
      float ea = 0.0f;
#pragma unroll
      for (int f = 0; f < 16; f++) ea = fmaf(a[f], w[c][f], ea);
      ea_sum[c] += ea;
      float m = xv[c] + xrv[c] + ea;
      m = (m >= 0.0f) ? m : 0.2f * m;
      lg = fmaf(m, attv[c], lg);
    }
    float nm = fmaxf(mx, lg);
    float s = expf(mx - nm);     // 0 when mx is sentinel and lg real
    float wE = expf(lg - nm);
    den = den * s + wE;
#pragma unroll
    for (int c = 0; c < C; c++) acc[c] = fmaf(acc[c], s, wE * xv[c]);
    mx = nm;
  }

  // ---- merge the L partial online-softmax states (xor butterfly) ----
#pragma unroll
  for (int off = 1; off < L; off <<= 1) {
    float omx  = __shfl_xor(mx, off, 64);
    float oden = __shfl_xor(den, off, 64);
    float nm = fmaxf(mx, omx);
    float s1 = expf(mx - nm);    // both sentinel -> exp(0)=1, scales zeros
    float s2 = expf(omx - nm);
    den = den * s1 + oden * s2;
#pragma unroll
    for (int c = 0; c < C; c++) {
      float oa = __shfl_xor(acc[c], off, 64);
      float oe = __shfl_xor(ea_sum[c], off, 64);
      acc[c] = acc[c] * s1 + oa * s2;
      ea_sum[c] += oe;
    }
    mx = nm;
  }

  // virtual self-loop: src = n, attr projection = mean of edge projections
  // (computed redundantly on all L lanes -- identical merged state)
  {
    float invd = 1.0f / fmaxf((float)dg, 1.0f);
    const float* xs = xl + (size_t)n * HC + h * C;
    float xv[C];
#pragma unroll
    for (int c = 0; c < C; c++) xv[c] = xs[c];
    float lg = 0.0f;
#pragma unroll
    for (int c = 0; c < C; c++) {
      float m = xv[c] + xrv[c] + ea_sum[c] * invd;
      m = (m >= 0.0f) ? m : 0.2f * m;
      lg = fmaf(m, attv[c], lg);
    }
    float nm = fmaxf(mx, lg);
    float s = expf(mx - nm);
    float wE = expf(lg - nm);
    den = den * s + wE;
#pragma unroll
    for (int c = 0; c < C; c++) acc[c] = fmaf(acc[c], s, wE * xv[c]);
  }

  float inv = 1.0f / den;
  float* od = out + (size_t)n * HC + h * C;
  // lane-partitioned channel writes
  for (int c = l; c < C; c += L) {
    float v = acc[c] * inv;
    if (bias) v = fmaxf(v + bias[h * C + c], 0.0f);
    od[c] = v;
  }
}

// ================= FC head =================

__global__ void __launch_bounds__(TPB) k_fc1(
    const float* __restrict__ h2, const float* __restrict__ W,
    float* __restrict__ h3, int NN, int Kc)
{
  int o = blockIdx.x;
  int ks = blockIdx.y;
  int k0 = ks * Kc;
  int k1 = min(NN, k0 + Kc);
  float acc[16];
#pragma unroll
  for (int b = 0; b < 16; b++) acc[b] = 0.0f;
  const float* wo = W + (size_t)o * NN;
  for (int k = k0 + threadIdx.x; k < k1; k += TPB) {
    float w = wo[k];
#pragma unroll
    for (int b = 0; b < 16; b++) acc[b] = fmaf(h2[(size_t)b * NN + k], w, acc[b]);
  }
#pragma unroll
  for (int b = 0; b < 16; b++) {
    float v = acc[b];
#pragma unroll
    for (int off = 32; off > 0; off >>= 1) v += __shfl_down(v, off, 64);
    if ((threadIdx.x & 63) == 0) atomicAdd(&h3[b * 100 + o], v);
  }
}

__global__ void __launch_bounds__(TPB) k_fc23(
    const float* __restrict__ h3, const float* __restrict__ fcb1,
    const float* __restrict__ W2, const float* __restrict__ b2,
    const float* __restrict__ W3, const float* __restrict__ b3,
    float* __restrict__ out, int B)
{
  __shared__ float s3[32 * 100];
  __shared__ float s4[32 * 10];
  int tid = threadIdx.x;
  for (int t = tid; t < B * 100; t += TPB)
    s3[t] = fmaxf(h3[t] + fcb1[t % 100], 0.0f);
  __syncthreads();
  if (tid < B * 10) {
    int b = tid / 10, o = tid % 10;
    float s = b2[o];
#pragma unroll
    for (int k = 0; k < 100; k++) s = fmaf(s3[b * 100 + k], W2[o * 100 + k], s);
    s4[tid] = fmaxf(s, 0.0f);
  }
  __syncthreads();
  if (tid < B) {
    float s = b3[0];
#pragma unroll
    for (int k = 0; k < 10; k++) s = fmaf(s4[tid * 10 + k], W3[k], s);
    out[tid] = s;
  }
}

// ================= launch =================

extern "C" void kernel_launch(void* const* d_in, const int* in_sizes, int n_in,
                              void* d_out, int out_size, void* d_ws, size_t ws_size,
                              hipStream_t stream) {
  const float* x      = (const float*)d_in[0];
  const int*   ei     = (const int*)d_in[1];
  const float* eattr  = (const float*)d_in[2];
  const float* W1l = (const float*)d_in[4];  const float* b1l = (const float*)d_in[5];
  const float* W1r = (const float*)d_in[6];  const float* b1r = (const float*)d_in[7];
  const float* We1 = (const float*)d_in[8];  const float* att1 = (const float*)d_in[9];
  const float* bias1 = (const float*)d_in[10];
  const float* W2l = (const float*)d_in[11]; const float* b2l = (const float*)d_in[12];
  const float* W2r = (const float*)d_in[13]; const float* b2r = (const float*)d_in[14];
  const float* We2 = (const float*)d_in[15]; const float* att2 = (const float*)d_in[16];
  const float* bias2 = (const float*)d_in[17];
  const float* fcW1 = (const float*)d_in[18]; const float* fcb1 = (const float*)d_in[19];
  const float* fcW2 = (const float*)d_in[20]; const float* fcb2 = (const float*)d_in[21];
  const float* fcW3 = (const float*)d_in[22]; const float* fcb3 = (const float*)d_in[23];
  float* out = (float*)d_out;

  const int N = in_sizes[0] / 64;                   // 80000
  const int E = in_sizes[2] / 16;                   // 2560000
  const int num_nodes = in_sizes[18] / (100 * 20);  // 5000
  const int B = N / num_nodes;                      // 16
  const int NB = (N + NPB - 1) / NPB;               // 313

  // ---- workspace layout (64B aligned chunks) ----
  char* base = (char*)d_ws;
  size_t off = 0;
  auto alloc = [&](size_t bytes) {
    size_t o = off; off += (bytes + 63) & ~(size_t)63; return o;
  };
  // zero-init region: padded bucket counters + h3
  size_t o_bcnt   = alloc((size_t)NB * CPAD * 4);
  size_t o_h3     = alloc((size_t)B * 100 * 4);
  size_t zeroBytes = off;
  size_t o_bbase  = alloc((size_t)NB * 4);
  size_t o_stage  = alloc((size_t)NB * BCAP * 8);
  size_t o_rowptr = alloc((size_t)N * 4);
  size_t o_deg    = alloc((size_t)N * 4);
  size_t o_srcc   = alloc((size_t)E * 4);
  size_t o_eidc   = alloc((size_t)E * 4);
  size_t o_xl1    = alloc((size_t)N * 9 * 4);
  size_t o_xr1    = alloc((size_t)N * 9 * 4);
  size_t o_xl2    = alloc((size_t)N * 20 * 4);
  size_t o_xr2    = alloc((size_t)N * 20 * 4);
  size_t o_h1     = alloc((size_t)N * 9 * 4);
  size_t o_h2     = alloc((size_t)N * 20 * 4);

  int*   bcnt   = (int*)(base + o_bcnt);
  float* h3     = (float*)(base + o_h3);
  int*   bbase  = (int*)(base + o_bbase);
  int2*  stage  = (int2*)(base + o_stage);
  int*   rowptr = (int*)(base + o_rowptr);
  int*   deg    = (int*)(base + o_deg);
  int*   srcc   = (int*)(base + o_srcc);
  int*   eidc   = (int*)(base + o_eidc);
  float* xl1    = (float*)(base + o_xl1);
  float* xr1    = (float*)(base + o_xr1);
  float* xl2    = (float*)(base + o_xl2);
  float* xr2    = (float*)(base + o_xr2);
  float* h1     = (float*)(base + o_h1);
  float* h2     = (float*)(base + o_h2);

  hipMemsetAsync(d_ws, 0, zeroBytes, stream);

  // node linears layer 1 (independent)
  k_lin1<<<gridFor((size_t)N * 18), TPB, 0, stream>>>(x, W1l, b1l, W1r, b1r, xl1, xr1, N);

  // binned CSR build
  int binBlocks = (int)(((size_t)E + TPB * ITEMS - 1) / (TPB * ITEMS));
  k_bin<<<binBlocks, TPB, 0, stream>>>(ei, bcnt, stage, E, NB);
  k_scanb<<<1, MAXNB, 0, stream>>>(bcnt, bbase, NB);
  k_csr<<<NB, TPB, 0, stream>>>(stage, bcnt, bbase, rowptr, deg, srcc, eidc, N);

  // ---- GATv2 layer 1 (H=3, C=3), 4 lanes per (n,h) row, raw gather ----
  k_attn<3, 3, 4><<<gridFor((size_t)N * 3 * 4), TPB, 0, stream>>>(
      rowptr, deg, srcc, eidc, eattr, xl1, xr1, We1, att1, nullptr, h1, N);

  // node linears layer 2
  k_lin2<<<gridFor((size_t)N * 40), TPB, 0, stream>>>(h1, bias1, W2l, b2l, W2r, b2r, xl2, xr2, N);

  // ---- GATv2 layer 2 (H=4, C=5), fused bias2+relu, raw gather ----
  k_attn<4, 5, 4><<<gridFor((size_t)N * 4 * 4), TPB, 0, stream>>>(
      rowptr, deg, srcc, eidc, eattr, xl2, xr2, We2, att2, bias2, h2, N);

  // FC head
  const int NN = num_nodes * 20;   // 100000
  const int KS = 16;
  const int Kc = (NN + KS - 1) / KS;
  dim3 g1(100, KS);
  k_fc1<<<g1, TPB, 0, stream>>>(h2, fcW1, h3, NN, Kc);
  k_fc23<<<1, TPB, 0, stream>>>(h3, fcb1, fcW2, fcb2, fcW3, fcb3, out, B);
  (void)out_size; (void)n_in;
}

// Round 9
// 745.042 us; speedup vs baseline: 1.1350x; 1.0060x over previous
//
#include <hip/hip_runtime.h>
#include <math.h>

#define TPB   256
#define NPB   256      // nodes per bucket (shift 8)
#define MAXNB 512      // supports N <= 131072
#define BCAP  10240    // staging capacity per bucket (expected 8192, sigma~90 -> no overflow)
#define ITEMS 16       // edges per thread in phase-1 tile (625 blocks -> 2.4/CU)
#define CPAD  16       // pad bucket counters to one per 64B line

static inline int gridFor(size_t n) { return (int)((n + TPB - 1) / TPB); }

// ================= node linear transforms =================

__global__ void __launch_bounds__(TPB) k_lin1(
    const float* __restrict__ x,
    const float* __restrict__ Wl, const float* __restrict__ bl,
    const float* __restrict__ Wr, const float* __restrict__ br,
    float* __restrict__ xl, float* __restrict__ xr, int N)
{
  int idx = blockIdx.x * TPB + threadIdx.x;
  if (idx >= N * 18) return;
  int i = idx / 18, t = idx % 18;
  bool left = t < 9;
  int j = left ? t : t - 9;
  const float4* W4 = (const float4*)((left ? Wl : Wr) + j * 64);
  float s = (left ? bl : br)[j];
  const float4* xi4 = (const float4*)(x + (size_t)i * 64);
#pragma unroll
  for (int f = 0; f < 16; f++) {
    float4 xv = xi4[f], wv = W4[f];
    s = fmaf(xv.x, wv.x, s);
    s = fmaf(xv.y, wv.y, s);
    s = fmaf(xv.z, wv.z, s);
    s = fmaf(xv.w, wv.w, s);
  }
  (left ? xl : xr)[(size_t)i * 9 + j] = s;
}

__global__ void __launch_bounds__(TPB) k_lin2(
    const float* __restrict__ h1, const float* __restrict__ bias1,
    const float* __restrict__ Wl, const float* __restrict__ bl,
    const float* __restrict__ Wr, const float* __restrict__ br,
    float* __restrict__ xl, float* __restrict__ xr, int N)
{
  int idx = blockIdx.x * TPB + threadIdx.x;
  if (idx >= N * 40) return;
  int i = idx / 40, t = idx % 40;
  float hr[9];
#pragma unroll
  for (int k = 0; k < 9; k++) hr[k] = fmaxf(h1[(size_t)i * 9 + k] + bias1[k], 0.0f);
  bool left = t < 20;
  int j = left ? t : t - 20;
  const float* W = (left ? Wl : Wr) + j * 9;
  float s = (left ? bl : br)[j];
#pragma unroll
  for (int k = 0; k < 9; k++) s = fmaf(hr[k], W[k], s);
  (left ? xl : xr)[(size_t)i * 20 + j] = s;
}

// ============== phase 1: bin edges by dst-bucket (LDS multisplit) ==========
// record: x = eid | (dst_local << 22), y = src.  (E < 2^22, dst_local < 256)

__global__ void __launch_bounds__(TPB) k_bin(
    const int* __restrict__ ei, int* __restrict__ bucketCntP,
    int2* __restrict__ staging, int E, int NB)
{
  __shared__ int hist[MAXNB];
  __shared__ int base[MAXNB];
  int tid = threadIdx.x;
  size_t tile0 = (size_t)blockIdx.x * (TPB * ITEMS);
  for (int i = tid; i < NB; i += TPB) hist[i] = 0;
  __syncthreads();
  for (int it = 0; it < ITEMS; ++it) {
    size_t e = tile0 + (size_t)it * TPB + tid;
    if (e < (size_t)E) {
      int dst = ei[(size_t)E + e];
      atomicAdd(&hist[dst >> 8], 1);
    }
  }
  __syncthreads();
  for (int i = tid; i < NB; i += TPB) {
    int c = hist[i];
    base[i] = c ? atomicAdd(&bucketCntP[(size_t)i * CPAD], c) : 0;
    hist[i] = 0;
  }
  __syncthreads();
  for (int it = 0; it < ITEMS; ++it) {
    size_t e = tile0 + (size_t)it * TPB + tid;
    if (e < (size_t)E) {
      int src = ei[e];
      int dst = ei[(size_t)E + e];
      int b = dst >> 8;
      int r = atomicAdd(&hist[b], 1);
      staging[(size_t)b * BCAP + base[b] + r] =
          make_int2((int)e | ((dst & 255) << 22), src);
    }
  }
}

// ============== scan bucket counts -> bucket edge bases ==============

__global__ void __launch_bounds__(MAXNB) k_scanb(
    const int* __restrict__ bucketCntP, int* __restrict__ bucketBase, int NB)
{
  __shared__ int s[MAXNB];
  int tid = threadIdx.x;
  int v = (tid < NB) ? bucketCntP[(size_t)tid * CPAD] : 0;
  s[tid] = v;
  __syncthreads();
  for (int off = 1; off < MAXNB; off <<= 1) {
    int u = (tid >= off) ? s[tid - off] : 0;
    __syncthreads();
    s[tid] += u;
    __syncthreads();
  }
  if (tid < NB) bucketBase[tid] = s[tid] - v;   // exclusive
}

// ============== phase 2: per-bucket tight CSR (L2-local writes) ============

__global__ void __launch_bounds__(TPB) k_csr(
    const int2* __restrict__ staging, const int* __restrict__ bucketCntP,
    const int* __restrict__ bucketBase,
    int* __restrict__ rowptr, int* __restrict__ degO,
    int* __restrict__ src_csr, int* __restrict__ eid_csr, int N)
{
  int b = blockIdx.x, tid = threadIdx.x;
  int n0 = b << 8;
  int recCnt = bucketCntP[(size_t)b * CPAD];
  int ebase = bucketBase[b];
  const int2* rec = staging + (size_t)b * BCAP;
  __shared__ int deg_s[NPB];
  __shared__ int pfx[NPB];
  __shared__ int cur[NPB];
  deg_s[tid] = 0;
  __syncthreads();
  for (int r = tid; r < recCnt; r += TPB)
    atomicAdd(&deg_s[(rec[r].x >> 22) & 255], 1);
  __syncthreads();
  pfx[tid] = deg_s[tid];
  __syncthreads();
  for (int off = 1; off < NPB; off <<= 1) {
    int u = (tid >= off) ? pfx[tid - off] : 0;
    __syncthreads();
    pfx[tid] += u;
    __syncthreads();
  }
  int excl = pfx[tid] - deg_s[tid];
  int n = n0 + tid;
  if (n < N) { rowptr[n] = ebase + excl; degO[n] = deg_s[tid]; }
  cur[tid] = ebase + excl;
  __syncthreads();
  for (int r = tid; r < recCnt; r += TPB) {
    int2 rc = rec[r];
    int dl = (rc.x >> 22) & 255;
    int eid = rc.x & 0x3FFFFF;
    int pos = atomicAdd(&cur[dl], 1);
    src_csr[pos] = rc.y;
    eid_csr[pos] = eid;
  }
}

// ========== fused GATv2 attention: online softmax, virtual self-loop =======
// L lanes cooperate on one (node, head) row; each lane keeps a partial
// online-softmax state over edges p = lane, lane+L, ...; states merged via
// a shfl_xor butterfly at the end (amortized -- NO per-edge cross-lane ops;
// round-7 showed per-edge __shfl compiles to ds_bpermute on the LDS pipe).
// Latency structure (round-8 counters: VALU 23%, occ 40%, BW 26% -> chain-
// latency-bound): the serial chain is eid_csr[pos] -> eattr[eid] (random
// 64B line) -> FMA.  Mitigations here: L=8 (4 iterations/lane instead of
// 8) and 1-ahead prefetch of next iteration's eid/src so the index-load
// latency hides under the current iteration's gather+compute.

template <int H, int C, int L>
__global__ void __launch_bounds__(TPB) k_attn(
    const int* __restrict__ rowptr, const int* __restrict__ deg,
    const int* __restrict__ src_csr, const int* __restrict__ eid_csr,
    const float* __restrict__ eattr,
    const float* __restrict__ xl, const float* __restrict__ xr,
    const float* __restrict__ We, const float* __restrict__ att,
    const float* __restrict__ bias,  // nullptr -> raw output
    float* __restrict__ out, int N)
{
  constexpr int HC = H * C;
  int idx = blockIdx.x * TPB + threadIdx.x;
  if (idx >= N * H * L) return;
  int l = idx & (L - 1);          // lane within group (L divides 64)
  int g = idx / L;                // (node, head) group
  int n = g / H, h = g - n * H;

  float w[C][16];
#pragma unroll
  for (int c = 0; c < C; c++)
#pragma unroll
    for (int f = 0; f < 16; f++) w[c][f] = We[(h * C + c) * 16 + f];
  float attv[C], xrv[C];
#pragma unroll
  for (int c = 0; c < C; c++) {
    attv[c] = att[h * C + c];
    xrv[c] = xr[(size_t)n * HC + h * C + c];
  }

  int r0 = rowptr[n];
  int dg = deg[n];

  // finite sentinel (not -inf) so empty-lane merges give exp(0)=1 on a zero
  // accumulator instead of exp(-inf+inf)=NaN.
  float mx = -3.0e38f, den = 0.0f;
  float acc[C], ea_sum[C];
#pragma unroll
  for (int c = 0; c < C; c++) { acc[c] = 0.0f; ea_sum[c] = 0.0f; }

  // software pipeline: indices for iteration i+1 issued before iteration
  // i's dependent gathers.
  int p = l;
  int ecur = 0, scur = 0;
  if (p < dg) { ecur = eid_csr[r0 + p]; scur = src_csr[r0 + p]; }
  while (p < dg) {
    int pn = p + L;
    int enx = 0, snx = 0;
    if (pn < dg) { enx = eid_csr[r0 + pn]; snx = src_csr[r0 + pn]; }

    float a[16];
    const float4* a4 = (const float4*)(eattr + (size_t)ecur * 16);
#pragma unroll
    for (int k = 0; k < 4; k++) {
      float4 v = a4[k];
      a[4 * k + 0] = v.x; a[4 * k + 1] = v.y; a[4 * k + 2] = v.z; a[4 * k + 3] = v.w;
    }
    const float* xs = xl + (size_t)scur * HC + h * C;
    float xv[C];
#pragma unroll
    for (int c = 0; c < C; c++) xv[c] = xs[c];
    float lg = 0.0f;
#pragma unroll
    for (int c = 0; c < C; c++) {
      float ea = 0.0f;
#pragma unroll
      for (int f = 0; f < 16; f++) ea = fmaf(a[f], w[c][f], ea);
      ea_sum[c] += ea;
      float m = xv[c] + xrv[c] + ea;
      m = (m >= 0.0f) ? m : 0.2f * m;
      lg = fmaf(m, attv[c], lg);
    }
    float nm = fmaxf(mx, lg);
    float s = expf(mx - nm);     // 0 when mx is sentinel and lg real
    float wE = expf(lg - nm);
    den = den * s + wE;
#pragma unroll
    for (int c = 0; c < C; c++) acc[c] = fmaf(acc[c], s, wE * xv[c]);
    mx = nm;

    p = pn; ecur = enx; scur = snx;
  }

  // ---- merge the L partial online-softmax states (xor butterfly) ----
#pragma unroll
  for (int off = 1; off < L; off <<= 1) {
    float omx  = __shfl_xor(mx, off, 64);
    float oden = __shfl_xor(den, off, 64);
    float nm = fmaxf(mx, omx);
    float s1 = expf(mx - nm);    // both sentinel -> exp(0)=1, scales zeros
    float s2 = expf(omx - nm);
    den = den * s1 + oden * s2;
#pragma unroll
    for (int c = 0; c < C; c++) {
      float oa = __shfl_xor(acc[c], off, 64);
      float oe = __shfl_xor(ea_sum[c], off, 64);
      acc[c] = acc[c] * s1 + oa * s2;
      ea_sum[c] += oe;
    }
    mx = nm;
  }

  // virtual self-loop: src = n, attr projection = mean of edge projections
  // (computed redundantly on all L lanes -- identical merged state)
  {
    float invd = 1.0f / fmaxf((float)dg, 1.0f);
    const float* xs = xl + (size_t)n * HC + h * C;
    float xv[C];
#pragma unroll
    for (int c = 0; c < C; c++) xv[c] = xs[c];
    float lg = 0.0f;
#pragma unroll
    for (int c = 0; c < C; c++) {
      float m = xv[c] + xrv[c] + ea_sum[c] * invd;
      m = (m >= 0.0f) ? m : 0.2f * m;
      lg = fmaf(m, attv[c], lg);
    }
    float nm = fmaxf(mx, lg);
    float s = expf(mx - nm);
    float wE = expf(lg - nm);
    den = den * s + wE;
#pragma unroll
    for (int c = 0; c < C; c++) acc[c] = fmaf(acc[c], s, wE * xv[c]);
  }

  float inv = 1.0f / den;
  float* od = out + (size_t)n * HC + h * C;
  // lane-partitioned channel writes
  for (int c = l; c < C; c += L) {
    float v = acc[c] * inv;
    if (bias) v = fmaxf(v + bias[h * C + c], 0.0f);
    od[c] = v;
  }
}

// ================= FC head =================

__global__ void __launch_bounds__(TPB) k_fc1(
    const float* __restrict__ h2, const float* __restrict__ W,
    float* __restrict__ h3, int NN, int Kc)
{
  int o = blockIdx.x;
  int ks = blockIdx.y;
  int k0 = ks * Kc;
  int k1 = min(NN, k0 + Kc);
  float acc[16];
#pragma unroll
  for (int b = 0; b < 16; b++) acc[b] = 0.0f;
  const float* wo = W + (size_t)o * NN;
  for (int k = k0 + threadIdx.x; k < k1; k += TPB) {
    float w = wo[k];
#pragma unroll
    for (int b = 0; b < 16; b++) acc[b] = fmaf(h2[(size_t)b * NN + k], w, acc[b]);
  }
#pragma unroll
  for (int b = 0; b < 16; b++) {
    float v = acc[b];
#pragma unroll
    for (int off = 32; off > 0; off >>= 1) v += __shfl_down(v, off, 64);
    if ((threadIdx.x & 63) == 0) atomicAdd(&h3[b * 100 + o], v);
  }
}

__global__ void __launch_bounds__(TPB) k_fc23(
    const float* __restrict__ h3, const float* __restrict__ fcb1,
    const float* __restrict__ W2, const float* __restrict__ b2,
    const float* __restrict__ W3, const float* __restrict__ b3,
    float* __restrict__ out, int B)
{
  __shared__ float s3[32 * 100];
  __shared__ float s4[32 * 10];
  int tid = threadIdx.x;
  for (int t = tid; t < B * 100; t += TPB)
    s3[t] = fmaxf(h3[t] + fcb1[t % 100], 0.0f);
  __syncthreads();
  if (tid < B * 10) {
    int b = tid / 10, o = tid % 10;
    float s = b2[o];
#pragma unroll
    for (int k = 0; k < 100; k++) s = fmaf(s3[b * 100 + k], W2[o * 100 + k], s);
    s4[tid] = fmaxf(s, 0.0f);
  }
  __syncthreads();
  if (tid < B) {
    float s = b3[0];
#pragma unroll
    for (int k = 0; k < 10; k++) s = fmaf(s4[tid * 10 + k], W3[k], s);
    out[tid] = s;
  }
}

// ================= launch =================

extern "C" void kernel_launch(void* const* d_in, const int* in_sizes, int n_in,
                              void* d_out, int out_size, void* d_ws, size_t ws_size,
                              hipStream_t stream) {
  const float* x      = (const float*)d_in[0];
  const int*   ei     = (const int*)d_in[1];
  const float* eattr  = (const float*)d_in[2];
  const float* W1l = (const float*)d_in[4];  const float* b1l = (const float*)d_in[5];
  const float* W1r = (const float*)d_in[6];  const float* b1r = (const float*)d_in[7];
  const float* We1 = (const float*)d_in[8];  const float* att1 = (const float*)d_in[9];
  const float* bias1 = (const float*)d_in[10];
  const float* W2l = (const float*)d_in[11]; const float* b2l = (const float*)d_in[12];
  const float* W2r = (const float*)d_in[13]; const float* b2r = (const float*)d_in[14];
  const float* We2 = (const float*)d_in[15]; const float* att2 = (const float*)d_in[16];
  const float* bias2 = (const float*)d_in[17];
  const float* fcW1 = (const float*)d_in[18]; const float* fcb1 = (const float*)d_in[19];
  const float* fcW2 = (const float*)d_in[20]; const float* fcb2 = (const float*)d_in[21];
  const float* fcW3 = (const float*)d_in[22]; const float* fcb3 = (const float*)d_in[23];
  float* out = (float*)d_out;

  const int N = in_sizes[0] / 64;                   // 80000
  const int E = in_sizes[2] / 16;                   // 2560000
  const int num_nodes = in_sizes[18] / (100 * 20);  // 5000
  const int B = N / num_nodes;                      // 16
  const int NB = (N + NPB - 1) / NPB;               // 313

  // ---- workspace layout (64B aligned chunks) ----
  char* base = (char*)d_ws;
  size_t off = 0;
  auto alloc = [&](size_t bytes) {
    size_t o = off; off += (bytes + 63) & ~(size_t)63; return o;
  };
  // zero-init region: padded bucket counters + h3
  size_t o_bcnt   = alloc((size_t)NB * CPAD * 4);
  size_t o_h3     = alloc((size_t)B * 100 * 4);
  size_t zeroBytes = off;
  size_t o_bbase  = alloc((size_t)NB * 4);
  size_t o_stage  = alloc((size_t)NB * BCAP * 8);
  size_t o_rowptr = alloc((size_t)N * 4);
  size_t o_deg    = alloc((size_t)N * 4);
  size_t o_srcc   = alloc((size_t)E * 4);
  size_t o_eidc   = alloc((size_t)E * 4);
  size_t o_xl1    = alloc((size_t)N * 9 * 4);
  size_t o_xr1    = alloc((size_t)N * 9 * 4);
  size_t o_xl2    = alloc((size_t)N * 20 * 4);
  size_t o_xr2    = alloc((size_t)N * 20 * 4);
  size_t o_h1     = alloc((size_t)N * 9 * 4);
  size_t o_h2     = alloc((size_t)N * 20 * 4);

  int*   bcnt   = (int*)(base + o_bcnt);
  float* h3     = (float*)(base + o_h3);
  int*   bbase  = (int*)(base + o_bbase);
  int2*  stage  = (int2*)(base + o_stage);
  int*   rowptr = (int*)(base + o_rowptr);
  int*   deg    = (int*)(base + o_deg);
  int*   srcc   = (int*)(base + o_srcc);
  int*   eidc   = (int*)(base + o_eidc);
  float* xl1    = (float*)(base + o_xl1);
  float* xr1    = (float*)(base + o_xr1);
  float* xl2    = (float*)(base + o_xl2);
  float* xr2    = (float*)(base + o_xr2);
  float* h1     = (float*)(base + o_h1);
  float* h2     = (float*)(base + o_h2);

  hipMemsetAsync(d_ws, 0, zeroBytes, stream);

  // node linears layer 1 (independent)
  k_lin1<<<gridFor((size_t)N * 18), TPB, 0, stream>>>(x, W1l, b1l, W1r, b1r, xl1, xr1, N);

  // binned CSR build
  int binBlocks = (int)(((size_t)E + TPB * ITEMS - 1) / (TPB * ITEMS));
  k_bin<<<binBlocks, TPB, 0, stream>>>(ei, bcnt, stage, E, NB);
  k_scanb<<<1, MAXNB, 0, stream>>>(bcnt, bbase, NB);
  k_csr<<<NB, TPB, 0, stream>>>(stage, bcnt, bbase, rowptr, deg, srcc, eidc, N);

  // ---- GATv2 layer 1 (H=3, C=3), 8 lanes per (n,h) row, raw gather ----
  k_attn<3, 3, 8><<<gridFor((size_t)N * 3 * 8), TPB, 0, stream>>>(
      rowptr, deg, srcc, eidc, eattr, xl1, xr1, We1, att1, nullptr, h1, N);

  // node linears layer 2
  k_lin2<<<gridFor((size_t)N * 40), TPB, 0, stream>>>(h1, bias1, W2l, b2l, W2r, b2r, xl2, xr2, N);

  // ---- GATv2 layer 2 (H=4, C=5), fused bias2+relu, raw gather ----
  k_attn<4, 5, 8><<<gridFor((size_t)N * 4 * 8), TPB, 0, stream>>>(
      rowptr, deg, srcc, eidc, eattr, xl2, xr2, We2, att2, bias2, h2, N);

  // FC head
  const int NN = num_nodes * 20;   // 100000
  const int KS = 16;
  const int Kc = (NN + KS - 1) / KS;
  dim3 g1(100, KS);
  k_fc1<<<g1, TPB, 0, stream>>>(h2, fcW1, h3, NN, Kc);
  k_fc23<<<1, TPB, 0, stream>>>(h3, fcb1, fcW2, fcb2, fcW3, fcb3, out, B);
  (void)out_size; (void)n_in;
}

// Round 10
// 740.226 us; speedup vs baseline: 1.1424x; 1.0065x over previous
//
#include <hip/hip_runtime.h>
#include <math.h>

#define TPB   256
#define NPB   256      // nodes per bucket (shift 8)
#define MAXNB 512      // supports N <= 131072
#define BCAP  10240    // staging capacity per bucket (expected 8192, sigma~90 -> no overflow)
#define ITEMS 16       // edges per thread in phase-1 tile (625 blocks -> 2.4/CU)
#define CPAD  16       // pad bucket counters to one per 64B line

static inline int gridFor(size_t n) { return (int)((n + TPB - 1) / TPB); }

// ================= node linear transforms =================
// Outputs padded per-head fragments: xl1p/xr1p = [n][3][4], xl2p/xr2p =
// [n][4][8] -- 16B-aligned so attn reads 1-2 float4 per (src, head).

__global__ void __launch_bounds__(TPB) k_lin1(
    const float* __restrict__ x,
    const float* __restrict__ Wl, const float* __restrict__ bl,
    const float* __restrict__ Wr, const float* __restrict__ br,
    float* __restrict__ xl, float* __restrict__ xr, int N)
{
  int idx = blockIdx.x * TPB + threadIdx.x;
  if (idx >= N * 18) return;
  int i = idx / 18, t = idx % 18;
  bool left = t < 9;
  int j = left ? t : t - 9;
  const float4* W4 = (const float4*)((left ? Wl : Wr) + j * 64);
  float s = (left ? bl : br)[j];
  const float4* xi4 = (const float4*)(x + (size_t)i * 64);
#pragma unroll
  for (int f = 0; f < 16; f++) {
    float4 xv = xi4[f], wv = W4[f];
    s = fmaf(xv.x, wv.x, s);
    s = fmaf(xv.y, wv.y, s);
    s = fmaf(xv.z, wv.z, s);
    s = fmaf(xv.w, wv.w, s);
  }
  int h = j / 3, c = j - h * 3;
  (left ? xl : xr)[(size_t)i * 12 + h * 4 + c] = s;   // [n][3][4] padded
}

__global__ void __launch_bounds__(TPB) k_lin2(
    const float* __restrict__ h1, const float* __restrict__ bias1,
    const float* __restrict__ Wl, const float* __restrict__ bl,
    const float* __restrict__ Wr, const float* __restrict__ br,
    float* __restrict__ xl, float* __restrict__ xr, int N)
{
  int idx = blockIdx.x * TPB + threadIdx.x;
  if (idx >= N * 40) return;
  int i = idx / 40, t = idx % 40;
  float hr[9];
#pragma unroll
  for (int k = 0; k < 9; k++) hr[k] = fmaxf(h1[(size_t)i * 9 + k] + bias1[k], 0.0f);
  bool left = t < 20;
  int j = left ? t : t - 20;
  const float* W = (left ? Wl : Wr) + j * 9;
  float s = (left ? bl : br)[j];
#pragma unroll
  for (int k = 0; k < 9; k++) s = fmaf(hr[k], W[k], s);
  int h = j / 5, c = j - h * 5;
  (left ? xl : xr)[(size_t)i * 32 + h * 8 + c] = s;   // [n][4][8] padded
}

// ============== phase 1: bin edges by dst-bucket (LDS multisplit) ==========
// record: x = eid | (dst_local << 22), y = src.  (E < 2^22, dst_local < 256)

__global__ void __launch_bounds__(TPB) k_bin(
    const int* __restrict__ ei, int* __restrict__ bucketCntP,
    int2* __restrict__ staging, int E, int NB)
{
  __shared__ int hist[MAXNB];
  __shared__ int base[MAXNB];
  int tid = threadIdx.x;
  size_t tile0 = (size_t)blockIdx.x * (TPB * ITEMS);
  for (int i = tid; i < NB; i += TPB) hist[i] = 0;
  __syncthreads();
  for (int it = 0; it < ITEMS; ++it) {
    size_t e = tile0 + (size_t)it * TPB + tid;
    if (e < (size_t)E) {
      int dst = ei[(size_t)E + e];
      atomicAdd(&hist[dst >> 8], 1);
    }
  }
  __syncthreads();
  for (int i = tid; i < NB; i += TPB) {
    int c = hist[i];
    base[i] = c ? atomicAdd(&bucketCntP[(size_t)i * CPAD], c) : 0;
    hist[i] = 0;
  }
  __syncthreads();
  for (int it = 0; it < ITEMS; ++it) {
    size_t e = tile0 + (size_t)it * TPB + tid;
    if (e < (size_t)E) {
      int src = ei[e];
      int dst = ei[(size_t)E + e];
      int b = dst >> 8;
      int r = atomicAdd(&hist[b], 1);
      staging[(size_t)b * BCAP + base[b] + r] =
          make_int2((int)e | ((dst & 255) << 22), src);
    }
  }
}

// ============== scan bucket counts -> bucket edge bases ==============

__global__ void __launch_bounds__(MAXNB) k_scanb(
    const int* __restrict__ bucketCntP, int* __restrict__ bucketBase, int NB)
{
  __shared__ int s[MAXNB];
  int tid = threadIdx.x;
  int v = (tid < NB) ? bucketCntP[(size_t)tid * CPAD] : 0;
  s[tid] = v;
  __syncthreads();
  for (int off = 1; off < MAXNB; off <<= 1) {
    int u = (tid >= off) ? s[tid - off] : 0;
    __syncthreads();
    s[tid] += u;
    __syncthreads();
  }
  if (tid < NB) bucketBase[tid] = s[tid] - v;   // exclusive
}

// ============== phase 2: per-bucket tight CSR (L2-local writes) ============
// es[pos] = (src, eid) packed -> one 8B load per edge in attn.

__global__ void __launch_bounds__(TPB) k_csr(
    const int2* __restrict__ staging, const int* __restrict__ bucketCntP,
    const int* __restrict__ bucketBase,
    int* __restrict__ rowptr, int* __restrict__ degO,
    int2* __restrict__ es, int N)
{
  int b = blockIdx.x, tid = threadIdx.x;
  int n0 = b << 8;
  int recCnt = bucketCntP[(size_t)b * CPAD];
  int ebase = bucketBase[b];
  const int2* rec = staging + (size_t)b * BCAP;
  __shared__ int deg_s[NPB];
  __shared__ int pfx[NPB];
  __shared__ int cur[NPB];
  deg_s[tid] = 0;
  __syncthreads();
  for (int r = tid; r < recCnt; r += TPB)
    atomicAdd(&deg_s[(rec[r].x >> 22) & 255], 1);
  __syncthreads();
  pfx[tid] = deg_s[tid];
  __syncthreads();
  for (int off = 1; off < NPB; off <<= 1) {
    int u = (tid >= off) ? pfx[tid - off] : 0;
    __syncthreads();
    pfx[tid] += u;
    __syncthreads();
  }
  int excl = pfx[tid] - deg_s[tid];
  int n = n0 + tid;
  if (n < N) { rowptr[n] = ebase + excl; degO[n] = deg_s[tid]; }
  cur[tid] = ebase + excl;
  __syncthreads();
  for (int r = tid; r < recCnt; r += TPB) {
    int2 rc = rec[r];
    int dl = (rc.x >> 22) & 255;
    int eid = rc.x & 0x3FFFFF;
    int pos = atomicAdd(&cur[dl], 1);
    es[pos] = make_int2(rc.y, eid);
  }
}

// ========== fused GATv2 attention: online softmax, virtual self-loop =======
// L=4 lanes per (node, head) row; lane processes edges p = l, l+4, ...
// 2-deep software pipeline (round-9 lesson: index prefetch alone is
// neutral -- the 64B attr gather latency itself must be overlapped):
//   at iter i: issue gather(i+1) from es(i+1), prefetch es(i+2),
//   compute on already-arrived data(i).
// No per-edge cross-lane ops (round-7: __shfl = ds_bpermute); merge
// butterfly amortized at end.  CP = padded per-head fragment stride.

template <int H, int C, int L, int CP>
__global__ void __launch_bounds__(TPB) k_attn(
    const int* __restrict__ rowptr, const int* __restrict__ deg,
    const int2* __restrict__ es,
    const float* __restrict__ eattr,
    const float* __restrict__ xlp, const float* __restrict__ xrp,
    const float* __restrict__ We, const float* __restrict__ att,
    const float* __restrict__ bias,  // nullptr -> raw output
    float* __restrict__ out, int N)
{
  constexpr int HC = H * C;
  int idx = blockIdx.x * TPB + threadIdx.x;
  if (idx >= N * H * L) return;
  int l = idx & (L - 1);
  int g = idx / L;
  int n = g / H, h = g - n * H;

  float w[C][16];
#pragma unroll
  for (int c = 0; c < C; c++)
#pragma unroll
    for (int f = 0; f < 16; f++) w[c][f] = We[(h * C + c) * 16 + f];
  float attv[C];
#pragma unroll
  for (int c = 0; c < C; c++) attv[c] = att[h * C + c];

  float xrv[C];
  {
    const float4* r4 = (const float4*)(xrp + ((size_t)n * H + h) * CP);
    float4 R0 = r4[0];
    float rf[8];
    rf[0] = R0.x; rf[1] = R0.y; rf[2] = R0.z; rf[3] = R0.w;
    if constexpr (CP == 8) {
      float4 R1 = r4[1];
      rf[4] = R1.x; rf[5] = R1.y; rf[6] = R1.z; rf[7] = R1.w;
    }
#pragma unroll
    for (int c = 0; c < C; c++) xrv[c] = rf[c];
  }

  int r0 = rowptr[n];
  int dg = deg[n];

  // finite sentinel (not -inf) so empty-lane merges give exp(0)=1 on a zero
  // accumulator instead of exp(-inf+inf)=NaN.
  float mx = -3.0e38f, den = 0.0f;
  float acc[C], ea_sum[C];
#pragma unroll
  for (int c = 0; c < C; c++) { acc[c] = 0.0f; ea_sum[c] = 0.0f; }

  // ---- pipeline prologue ----
  int p = l;
  int2 e0 = make_int2(0, 0), e1 = make_int2(0, 0);
  if (p < dg)     e0 = es[r0 + p];
  if (p + L < dg) e1 = es[r0 + p + L];
  float4 A0, A1, A2, A3, X0, X1;
  if (p < dg) {
    const float4* a4 = (const float4*)(eattr + (size_t)e0.y * 16);
    A0 = a4[0]; A1 = a4[1]; A2 = a4[2]; A3 = a4[3];
    const float4* x4 = (const float4*)(xlp + ((size_t)e0.x * H + h) * CP);
    X0 = x4[0];
    if constexpr (CP == 8) X1 = x4[1];
  }

  while (p < dg) {
    int pn = p + L;
    // issue next iteration's data gather (e1 already resident)
    float4 B0, B1, B2, B3, Y0, Y1;
    if (pn < dg) {
      const float4* a4 = (const float4*)(eattr + (size_t)e1.y * 16);
      B0 = a4[0]; B1 = a4[1]; B2 = a4[2]; B3 = a4[3];
      const float4* x4 = (const float4*)(xlp + ((size_t)e1.x * H + h) * CP);
      Y0 = x4[0];
      if constexpr (CP == 8) Y1 = x4[1];
    }
    // prefetch index record for i+2
    int2 e2 = make_int2(0, 0);
    if (pn + L < dg) e2 = es[r0 + pn + L];

    // ---- compute on iteration i's data ----
    float a[16];
    a[0] = A0.x; a[1] = A0.y; a[2]  = A0.z; a[3]  = A0.w;
    a[4] = A1.x; a[5] = A1.y; a[6]  = A1.z; a[7]  = A1.w;
    a[8] = A2.x; a[9] = A2.y; a[10] = A2.z; a[11] = A2.w;
    a[12] = A3.x; a[13] = A3.y; a[14] = A3.z; a[15] = A3.w;
    float xf[8];
    xf[0] = X0.x; xf[1] = X0.y; xf[2] = X0.z; xf[3] = X0.w;
    if constexpr (CP == 8) {
      xf[4] = X1.x; xf[5] = X1.y; xf[6] = X1.z; xf[7] = X1.w;
    }
    float xv[C];
#pragma unroll
    for (int c = 0; c < C; c++) xv[c] = xf[c];

    float lg = 0.0f;
#pragma unroll
    for (int c = 0; c < C; c++) {
      float ea = 0.0f;
#pragma unroll
      for (int f = 0; f < 16; f++) ea = fmaf(a[f], w[c][f], ea);
      ea_sum[c] += ea;
      float m = xv[c] + xrv[c] + ea;
      m = (m >= 0.0f) ? m : 0.2f * m;
      lg = fmaf(m, attv[c], lg);
    }
    float nm = fmaxf(mx, lg);
    float s = expf(mx - nm);     // 0 when mx is sentinel and lg real
    float wE = expf(lg - nm);
    den = den * s + wE;
#pragma unroll
    for (int c = 0; c < C; c++) acc[c] = fmaf(acc[c], s, wE * xv[c]);
    mx = nm;

    // rotate pipeline
    p = pn;
    e0 = e1; e1 = e2;
    A0 = B0; A1 = B1; A2 = B2; A3 = B3;
    X0 = Y0;
    if constexpr (CP == 8) X1 = Y1;
  }

  // ---- merge the L partial online-softmax states (xor butterfly) ----
#pragma unroll
  for (int off = 1; off < L; off <<= 1) {
    float omx  = __shfl_xor(mx, off, 64);
    float oden = __shfl_xor(den, off, 64);
    float nm = fmaxf(mx, omx);
    float s1 = expf(mx - nm);    // both sentinel -> exp(0)=1, scales zeros
    float s2 = expf(omx - nm);
    den = den * s1 + oden * s2;
#pragma unroll
    for (int c = 0; c < C; c++) {
      float oa = __shfl_xor(acc[c], off, 64);
      float oe = __shfl_xor(ea_sum[c], off, 64);
      acc[c] = acc[c] * s1 + oa * s2;
      ea_sum[c] += oe;
    }
    mx = nm;
  }

  // virtual self-loop: src = n, attr projection = mean of edge projections
  // (computed redundantly on all L lanes -- identical merged state)
  {
    float invd = 1.0f / fmaxf((float)dg, 1.0f);
    const float4* x4 = (const float4*)(xlp + ((size_t)n * H + h) * CP);
    float4 S0 = x4[0];
    float sf[8];
    sf[0] = S0.x; sf[1] = S0.y; sf[2] = S0.z; sf[3] = S0.w;
    if constexpr (CP == 8) {
      float4 S1 = x4[1];
      sf[4] = S1.x; sf[5] = S1.y; sf[6] = S1.z; sf[7] = S1.w;
    }
    float xv[C];
#pragma unroll
    for (int c = 0; c < C; c++) xv[c] = sf[c];
    float lg = 0.0f;
#pragma unroll
    for (int c = 0; c < C; c++) {
      float m = xv[c] + xrv[c] + ea_sum[c] * invd;
      m = (m >= 0.0f) ? m : 0.2f * m;
      lg = fmaf(m, attv[c], lg);
    }
    float nm = fmaxf(mx, lg);
    float s = expf(mx - nm);
    float wE = expf(lg - nm);
    den = den * s + wE;
#pragma unroll
    for (int c = 0; c < C; c++) acc[c] = fmaf(acc[c], s, wE * xv[c]);
  }

  float inv = 1.0f / den;
  float* od = out + (size_t)n * HC + h * C;   // dense output (consumed densely)
  for (int c = l; c < C; c += L) {
    float v = acc[c] * inv;
    if (bias) v = fmaxf(v + bias[h * C + c], 0.0f);
    od[c] = v;
  }
}

// ================= FC head =================

__global__ void __launch_bounds__(TPB) k_fc1(
    const float* __restrict__ h2, const float* __restrict__ W,
    float* __restrict__ h3, int NN, int Kc)
{
  int o = blockIdx.x;
  int ks = blockIdx.y;
  int k0 = ks * Kc;
  int k1 = min(NN, k0 + Kc);
  float acc[16];
#pragma unroll
  for (int b = 0; b < 16; b++) acc[b] = 0.0f;
  const float* wo = W + (size_t)o * NN;
  for (int k = k0 + threadIdx.x; k < k1; k += TPB) {
    float w = wo[k];
#pragma unroll
    for (int b = 0; b < 16; b++) acc[b] = fmaf(h2[(size_t)b * NN + k], w, acc[b]);
  }
#pragma unroll
  for (int b = 0; b < 16; b++) {
    float v = acc[b];
#pragma unroll
    for (int off = 32; off > 0; off >>= 1) v += __shfl_down(v, off, 64);
    if ((threadIdx.x & 63) == 0) atomicAdd(&h3[b * 100 + o], v);
  }
}

__global__ void __launch_bounds__(TPB) k_fc23(
    const float* __restrict__ h3, const float* __restrict__ fcb1,
    const float* __restrict__ W2, const float* __restrict__ b2,
    const float* __restrict__ W3, const float* __restrict__ b3,
    float* __restrict__ out, int B)
{
  __shared__ float s3[32 * 100];
  __shared__ float s4[32 * 10];
  int tid = threadIdx.x;
  for (int t = tid; t < B * 100; t += TPB)
    s3[t] = fmaxf(h3[t] + fcb1[t % 100], 0.0f);
  __syncthreads();
  if (tid < B * 10) {
    int b = tid / 10, o = tid % 10;
    float s = b2[o];
#pragma unroll
    for (int k = 0; k < 100; k++) s = fmaf(s3[b * 100 + k], W2[o * 100 + k], s);
    s4[tid] = fmaxf(s, 0.0f);
  }
  __syncthreads();
  if (tid < B) {
    float s = b3[0];
#pragma unroll
    for (int k = 0; k < 10; k++) s = fmaf(s4[tid * 10 + k], W3[k], s);
    out[tid] = s;
  }
}

// ================= launch =================

extern "C" void kernel_launch(void* const* d_in, const int* in_sizes, int n_in,
                              void* d_out, int out_size, void* d_ws, size_t ws_size,
                              hipStream_t stream) {
  const float* x      = (const float*)d_in[0];
  const int*   ei     = (const int*)d_in[1];
  const float* eattr  = (const float*)d_in[2];
  const float* W1l = (const float*)d_in[4];  const float* b1l = (const float*)d_in[5];
  const float* W1r = (const float*)d_in[6];  const float* b1r = (const float*)d_in[7];
  const float* We1 = (const float*)d_in[8];  const float* att1 = (const float*)d_in[9];
  const float* bias1 = (const float*)d_in[10];
  const float* W2l = (const float*)d_in[11]; const float* b2l = (const float*)d_in[12];
  const float* W2r = (const float*)d_in[13]; const float* b2r = (const float*)d_in[14];
  const float* We2 = (const float*)d_in[15]; const float* att2 = (const float*)d_in[16];
  const float* bias2 = (const float*)d_in[17];
  const float* fcW1 = (const float*)d_in[18]; const float* fcb1 = (const float*)d_in[19];
  const float* fcW2 = (const float*)d_in[20]; const float* fcb2 = (const float*)d_in[21];
  const float* fcW3 = (const float*)d_in[22]; const float* fcb3 = (const float*)d_in[23];
  float* out = (float*)d_out;

  const int N = in_sizes[0] / 64;                   // 80000
  const int E = in_sizes[2] / 16;                   // 2560000
  const int num_nodes = in_sizes[18] / (100 * 20);  // 5000
  const int B = N / num_nodes;                      // 16
  const int NB = (N + NPB - 1) / NPB;               // 313

  // ---- workspace layout (64B aligned chunks) ----
  char* base = (char*)d_ws;
  size_t off = 0;
  auto alloc = [&](size_t bytes) {
    size_t o = off; off += (bytes + 63) & ~(size_t)63; return o;
  };
  // zero-init region: padded bucket counters + h3
  size_t o_bcnt   = alloc((size_t)NB * CPAD * 4);
  size_t o_h3     = alloc((size_t)B * 100 * 4);
  size_t zeroBytes = off;
  size_t o_bbase  = alloc((size_t)NB * 4);
  size_t o_stage  = alloc((size_t)NB * BCAP * 8);
  size_t o_rowptr = alloc((size_t)N * 4);
  size_t o_deg    = alloc((size_t)N * 4);
  size_t o_es     = alloc((size_t)E * 8);
  size_t o_xl1    = alloc((size_t)N * 12 * 4);      // [n][3][4] padded
  size_t o_xr1    = alloc((size_t)N * 12 * 4);
  size_t o_xl2    = alloc((size_t)N * 32 * 4);      // [n][4][8] padded
  size_t o_xr2    = alloc((size_t)N * 32 * 4);
  size_t o_h1     = alloc((size_t)N * 9 * 4);
  size_t o_h2     = alloc((size_t)N * 20 * 4);

  int*   bcnt   = (int*)(base + o_bcnt);
  float* h3     = (float*)(base + o_h3);
  int*   bbase  = (int*)(base + o_bbase);
  int2*  stage  = (int2*)(base + o_stage);
  int*   rowptr = (int*)(base + o_rowptr);
  int*   deg    = (int*)(base + o_deg);
  int2*  es     = (int2*)(base + o_es);
  float* xl1    = (float*)(base + o_xl1);
  float* xr1    = (float*)(base + o_xr1);
  float* xl2    = (float*)(base + o_xl2);
  float* xr2    = (float*)(base + o_xr2);
  float* h1     = (float*)(base + o_h1);
  float* h2     = (float*)(base + o_h2);

  hipMemsetAsync(d_ws, 0, zeroBytes, stream);

  // node linears layer 1 (independent)
  k_lin1<<<gridFor((size_t)N * 18), TPB, 0, stream>>>(x, W1l, b1l, W1r, b1r, xl1, xr1, N);

  // binned CSR build
  int binBlocks = (int)(((size_t)E + TPB * ITEMS - 1) / (TPB * ITEMS));
  k_bin<<<binBlocks, TPB, 0, stream>>>(ei, bcnt, stage, E, NB);
  k_scanb<<<1, MAXNB, 0, stream>>>(bcnt, bbase, NB);
  k_csr<<<NB, TPB, 0, stream>>>(stage, bcnt, bbase, rowptr, deg, es, N);

  // ---- GATv2 layer 1 (H=3, C=3, CP=4), pipelined raw gather ----
  k_attn<3, 3, 4, 4><<<gridFor((size_t)N * 3 * 4), TPB, 0, stream>>>(
      rowptr, deg, es, eattr, xl1, xr1, We1, att1, nullptr, h1, N);

  // node linears layer 2
  k_lin2<<<gridFor((size_t)N * 40), TPB, 0, stream>>>(h1, bias1, W2l, b2l, W2r, b2r, xl2, xr2, N);

  // ---- GATv2 layer 2 (H=4, C=5, CP=8), fused bias2+relu ----
  k_attn<4, 5, 4, 8><<<gridFor((size_t)N * 4 * 4), TPB, 0, stream>>>(
      rowptr, deg, es, eattr, xl2, xr2, We2, att2, bias2, h2, N);

  // FC head
  const int NN = num_nodes * 20;   // 100000
  const int KS = 16;
  const int Kc = (NN + KS - 1) / KS;
  dim3 g1(100, KS);
  k_fc1<<<g1, TPB, 0, stream>>>(h2, fcW1, h3, NN, Kc);
  k_fc23<<<1, TPB, 0, stream>>>(h3, fcb1, fcW2, fcb2, fcW3, fcb3, out, B);
  (void)out_size; (void)n_in;
}